// Round 1
// baseline (1777.866 us; speedup 1.0000x reference)
//
#include <hip/hip_runtime.h>
#include <hip/hip_bf16.h>

#define N_NODES 50000
#define N_REL   4
#define N_EDGES 500000
#define EMB     128
#define HID     128
#define OUTD    64

// ---------------------------------------------------------------- degrees ---
__global__ void deg_kernel(const int* __restrict__ src, const int* __restrict__ dst,
                           float* __restrict__ deg_src, float* __restrict__ deg_dst) {
    int i = blockIdx.x * blockDim.x + threadIdx.x;
    if (i >= N_REL * N_EDGES) return;
    int r = i / N_EDGES;
    atomicAdd(&deg_src[r * N_NODES + src[i]], 1.0f);
    atomicAdd(&deg_dst[r * N_NODES + dst[i]], 1.0f);
}

__global__ void norm_kernel(float* __restrict__ a, int n) {
    int i = blockIdx.x * blockDim.x + threadIdx.x;
    if (i < n) {
        float v = a[i];
        a[i] = (v > 0.0f) ? rsqrtf(v) : 0.0f;
    }
}

// -------------------------------------------------------------- bias fill ---
// h[i][j] = 0.25 * sum_r b[r][j]
template <int HO>
__global__ void bias_fill(const float* __restrict__ b, float* __restrict__ h) {
    int i = blockIdx.x * blockDim.x + threadIdx.x;
    if (i >= N_NODES * HO) return;
    int j = i & (HO - 1);
    h[i] = 0.25f * (b[j] + b[HO + j] + b[2 * HO + j] + b[3 * HO + j]);
}

// ------------------------------------------------------------------- GEMM ---
// C[n][HO] = (X[n][HI] * ns[n,None]) @ W[HI][HO]
// block: 256 threads, 64 rows x HO cols per block, K-tiled by 32.
template <int HI, int HO>
__global__ __launch_bounds__(256) void gemm_scaled(
    const float* __restrict__ X,
    const float* __restrict__ ns,
    const float* __restrict__ W,
    float* __restrict__ C) {
    constexpr int BM = 64, KT = 32;
    constexpr int NJ = HO / 32;                 // cols per thread (4 or 2)
    __shared__ float xt[BM][KT + 1];
    __shared__ float wt[KT][HO];

    const int t = threadIdx.x;
    const int row0 = blockIdx.x * BM;
    const int tc = t & 31;                      // col lane 0..31
    const int tr = t >> 5;                      // row group 0..7

    float acc[8][NJ];
#pragma unroll
    for (int i = 0; i < 8; ++i)
#pragma unroll
        for (int j = 0; j < NJ; ++j) acc[i][j] = 0.0f;

    for (int k0 = 0; k0 < HI; k0 += KT) {
        // stage X tile (scaled by ns): BM*KT floats = 512 float4, 2/thread
#pragma unroll
        for (int q = 0; q < (BM * KT / 4) / 256; ++q) {
            int idx = t + q * 256;              // float4 index
            int row = idx >> 3;                 // 8 float4 per row
            int c4 = idx & 7;
            int grow = row0 + row;
            float4 v = make_float4(0.f, 0.f, 0.f, 0.f);
            float s = 0.0f;
            if (grow < N_NODES) {
                v = *reinterpret_cast<const float4*>(&X[(size_t)grow * HI + k0 + c4 * 4]);
                s = ns[grow];
            }
            xt[row][c4 * 4 + 0] = v.x * s;
            xt[row][c4 * 4 + 1] = v.y * s;
            xt[row][c4 * 4 + 2] = v.z * s;
            xt[row][c4 * 4 + 3] = v.w * s;
        }
        // stage W tile: KT*HO floats
#pragma unroll
        for (int q = 0; q < (KT * HO / 4) / 256; ++q) {
            int idx = t + q * 256;
            int k = idx / (HO / 4);
            int c4 = idx % (HO / 4);
            float4 v = *reinterpret_cast<const float4*>(&W[(size_t)(k0 + k) * HO + c4 * 4]);
            *reinterpret_cast<float4*>(&wt[k][c4 * 4]) = v;
        }
        __syncthreads();
#pragma unroll
        for (int kk = 0; kk < KT; ++kk) {
            float xv[8];
#pragma unroll
            for (int i = 0; i < 8; ++i) xv[i] = xt[tr + 8 * i][kk];
            float wv[NJ];
#pragma unroll
            for (int j = 0; j < NJ; ++j) wv[j] = wt[kk][tc + 32 * j];
#pragma unroll
            for (int i = 0; i < 8; ++i)
#pragma unroll
                for (int j = 0; j < NJ; ++j) acc[i][j] += xv[i] * wv[j];
        }
        __syncthreads();
    }
#pragma unroll
    for (int i = 0; i < 8; ++i) {
        int grow = row0 + tr + 8 * i;
        if (grow < N_NODES) {
#pragma unroll
            for (int j = 0; j < NJ; ++j)
                C[(size_t)grow * HO + tc + 32 * j] = acc[i][j];
        }
    }
}

// ---------------------------------------------------------------- scatter ---
// one 64-lane wave per edge: h[dst] += xs[src] * (0.25 * nd[dst])
template <int HO>
__global__ void scatter_kernel(const int* __restrict__ src, const int* __restrict__ dst,
                               const float* __restrict__ nd,
                               const float* __restrict__ xs,
                               float* __restrict__ h) {
    int gid = blockIdx.x * blockDim.x + threadIdx.x;
    int wave = gid >> 6;
    int lane = gid & 63;
    if (wave >= N_EDGES) return;
    int s = src[wave];
    int d = dst[wave];
    float scale = 0.25f * nd[d];
    const float* xr = xs + (size_t)s * HO;
    float* hr = h + (size_t)d * HO;
#pragma unroll
    for (int q = lane; q < HO; q += 64)
        atomicAdd(&hr[q], xr[q] * scale);
}

// ----------------------------------------------------------------- launch ---
extern "C" void kernel_launch(void* const* d_in, const int* in_sizes, int n_in,
                              void* d_out, int out_size, void* d_ws, size_t ws_size,
                              hipStream_t stream) {
    const int* src = (const int*)d_in[1];
    const int* dst = (const int*)d_in[2];
    const float* emb = (const float*)d_in[3];
    const float* W1 = (const float*)d_in[4];
    const float* b1 = (const float*)d_in[5];
    const float* W2 = (const float*)d_in[6];
    const float* b2 = (const float*)d_in[7];
    float* out = (float*)d_out;

    float* norm_src = (float*)d_ws;                    // [N_REL][N_NODES]
    float* norm_dst = norm_src + N_REL * N_NODES;      // [N_REL][N_NODES]
    float* xs = norm_dst + N_REL * N_NODES;            // [N_NODES][128]
    float* h1 = xs + (size_t)N_NODES * 128;            // [N_NODES][128]

    // degrees -> norms (graph is identical for both layers)
    hipMemsetAsync(norm_src, 0, 2 * N_REL * N_NODES * sizeof(float), stream);
    deg_kernel<<<(N_REL * N_EDGES + 255) / 256, 256, 0, stream>>>(src, dst, norm_src, norm_dst);
    norm_kernel<<<(2 * N_REL * N_NODES + 255) / 256, 256, 0, stream>>>(norm_src, 2 * N_REL * N_NODES);

    // ----- layer 1: emb[50000,128] -> h1[50000,128]
    bias_fill<HID><<<(N_NODES * HID + 255) / 256, 256, 0, stream>>>(b1, h1);
    for (int r = 0; r < N_REL; ++r) {
        gemm_scaled<EMB, HID><<<(N_NODES + 63) / 64, 256, 0, stream>>>(
            emb, norm_src + r * N_NODES, W1 + (size_t)r * EMB * HID, xs);
        scatter_kernel<HID><<<(N_EDGES * 64 + 255) / 256, 256, 0, stream>>>(
            src + (size_t)r * N_EDGES, dst + (size_t)r * N_EDGES,
            norm_dst + r * N_NODES, xs, h1);
    }

    // ----- layer 2: h1[50000,128] -> out[50000,64]
    bias_fill<OUTD><<<(N_NODES * OUTD + 255) / 256, 256, 0, stream>>>(b2, out);
    for (int r = 0; r < N_REL; ++r) {
        gemm_scaled<HID, OUTD><<<(N_NODES + 63) / 64, 256, 0, stream>>>(
            h1, norm_src + r * N_NODES, W2 + (size_t)r * HID * OUTD, xs);
        scatter_kernel<OUTD><<<(N_EDGES * 64 + 255) / 256, 256, 0, stream>>>(
            src + (size_t)r * N_EDGES, dst + (size_t)r * N_EDGES,
            norm_dst + r * N_NODES, xs, out);
    }
}

// Round 2
// 1552.603 us; speedup vs baseline: 1.1451x; 1.1451x over previous
//
#include <hip/hip_runtime.h>
#include <hip/hip_bf16.h>

#define N_NODES 50000
#define N_REL   4
#define N_EDGES 500000
#define EMB     128
#define HID     128
#define OUTD    64

// ------------------------------------------------------------ CSR build ----
__global__ void count_kernel(const int* __restrict__ src, const int* __restrict__ dst,
                             int* __restrict__ deg_out, int* __restrict__ deg_in) {
    int i = blockIdx.x * blockDim.x + threadIdx.x;
    if (i >= N_REL * N_EDGES) return;
    int r = i / N_EDGES;
    atomicAdd(&deg_out[r * N_NODES + src[i]], 1);
    atomicAdd(&deg_in[r * N_NODES + dst[i]], 1);
}

// one block per relation; exclusive scan of deg_in -> offs[r][0..N]
__global__ __launch_bounds__(1024) void scan_kernel(const int* __restrict__ deg_in,
                                                    int* __restrict__ offs) {
    __shared__ int sh[1024];
    const int r = blockIdx.x;
    const int t = threadIdx.x;
    const int CH = 49;                          // 49*1024 = 50176 >= 50001
    const int start = t * CH;
    int sum = 0;
    for (int j = start; j < start + CH; ++j)
        if (j < N_NODES) sum += deg_in[r * N_NODES + j];
    sh[t] = sum;
    __syncthreads();
    for (int off = 1; off < 1024; off <<= 1) {
        int v = (t >= off) ? sh[t - off] : 0;
        __syncthreads();
        sh[t] += v;
        __syncthreads();
    }
    int run = sh[t] - sum;                      // exclusive prefix
    for (int j = start; j < start + CH; ++j) {
        if (j <= N_NODES) {
            offs[r * (N_NODES + 1) + j] = run;
            if (j < N_NODES) run += deg_in[r * N_NODES + j];
        }
    }
}

__global__ void norm_cursor_kernel(const int* __restrict__ deg_out,
                                   const int* __restrict__ deg_in,
                                   const int* __restrict__ offs,
                                   float* __restrict__ nsrc, float* __restrict__ ndst,
                                   int* __restrict__ cursor) {
    int i = blockIdx.x * blockDim.x + threadIdx.x;
    if (i >= N_REL * N_NODES) return;
    int dOut = deg_out[i], dIn = deg_in[i];
    nsrc[i] = dOut > 0 ? rsqrtf((float)dOut) : 0.0f;
    ndst[i] = dIn > 0 ? rsqrtf((float)dIn) : 0.0f;
    int r = i / N_NODES, j = i % N_NODES;
    cursor[i] = offs[r * (N_NODES + 1) + j];
}

__global__ void place_kernel(const int* __restrict__ src, const int* __restrict__ dst,
                             int* __restrict__ cursor, int* __restrict__ csr) {
    int i = blockIdx.x * blockDim.x + threadIdx.x;
    if (i >= N_REL * N_EDGES) return;
    int r = i / N_EDGES;
    int p = atomicAdd(&cursor[r * N_NODES + dst[i]], 1);
    csr[(size_t)r * N_EDGES + p] = src[i];
}

// ------------------------------------------------------- fused layer -------
// out[d] = 0.25 * sum_r ( nd_r[d] * (sum_{e in r, dst=d} x[src_e]*ns_r[src_e]) @ W_r ) + 0.25*sum_r b_r
// block = 256 threads (4 waves), 64 output rows per block.
template <int HI, int HO>
__global__ __launch_bounds__(256) void rgcn_layer(
    const float* __restrict__ x,
    const int* __restrict__ csr,        // [R][E] src ids sorted by dst
    const int* __restrict__ offs,       // [R][N+1]
    const float* __restrict__ nsrc,     // [R][N]
    const float* __restrict__ ndst,     // [R][N]
    const float* __restrict__ W,        // [R][HI][HO]
    const float* __restrict__ b,        // [R][HO]
    float* __restrict__ out) {
    constexpr int KT = 32;
    constexpr int NJ = HO / 32;
    __shared__ float agg[64][HI + 1];
    __shared__ float wt[KT][HO];

    const int t = threadIdx.x;
    const int wave = t >> 6;
    const int lane = t & 63;
    const int tc = t & 31;
    const int tr = t >> 5;
    const int row0 = blockIdx.x * 64;

    float acc[8][NJ];
#pragma unroll
    for (int i = 0; i < 8; ++i)
#pragma unroll
        for (int j = 0; j < NJ; ++j) acc[i][j] = 0.0f;

    for (int r = 0; r < N_REL; ++r) {
        const int* csr_r = csr + (size_t)r * N_EDGES;
        const int* offs_r = offs + r * (N_NODES + 1);
        const float* ns_r = nsrc + r * N_NODES;
        const float* nd_r = ndst + r * N_NODES;
        // ---- gather: each wave owns 16 rows
        for (int rr = 0; rr < 16; ++rr) {
            int row = wave * 16 + rr;
            int d = row0 + row;
            float a0 = 0.0f, a1 = 0.0f;
            if (d < N_NODES) {
                int e = offs_r[d], e1 = offs_r[d + 1];
                for (; e + 1 < e1; e += 2) {
                    int s0 = csr_r[e], s1 = csr_r[e + 1];
                    float sc0 = ns_r[s0], sc1 = ns_r[s1];
                    const float* p0 = x + (size_t)s0 * HI;
                    const float* p1 = x + (size_t)s1 * HI;
                    a0 += p0[lane] * sc0;
                    a1 += p0[64 + lane] * sc0;
                    a0 += p1[lane] * sc1;
                    a1 += p1[64 + lane] * sc1;
                }
                if (e < e1) {
                    int s0 = csr_r[e];
                    float sc0 = ns_r[s0];
                    const float* p0 = x + (size_t)s0 * HI;
                    a0 += p0[lane] * sc0;
                    a1 += p0[64 + lane] * sc0;
                }
                float scd = 0.25f * nd_r[d];
                a0 *= scd; a1 *= scd;
            }
            agg[row][lane] = a0;
            agg[row][64 + lane] = a1;
        }
        __syncthreads();
        // ---- GEMM: acc += agg @ W_r
        for (int k0 = 0; k0 < HI; k0 += KT) {
#pragma unroll
            for (int q = 0; q < (KT * HO / 4) / 256; ++q) {
                int idx = t + q * 256;
                int k = idx / (HO / 4);
                int c4 = idx % (HO / 4);
                float4 v = *reinterpret_cast<const float4*>(
                    &W[((size_t)r * HI + k0 + k) * HO + c4 * 4]);
                *reinterpret_cast<float4*>(&wt[k][c4 * 4]) = v;
            }
            __syncthreads();
#pragma unroll
            for (int kk = 0; kk < KT; ++kk) {
                float xv[8];
#pragma unroll
                for (int i = 0; i < 8; ++i) xv[i] = agg[tr + 8 * i][k0 + kk];
                float wv[NJ];
#pragma unroll
                for (int j = 0; j < NJ; ++j) wv[j] = wt[kk][tc + 32 * j];
#pragma unroll
                for (int i = 0; i < 8; ++i)
#pragma unroll
                    for (int j = 0; j < NJ; ++j) acc[i][j] += xv[i] * wv[j];
            }
            __syncthreads();
        }
    }
    // ---- epilogue: single pure store, bias folded
#pragma unroll
    for (int i = 0; i < 8; ++i) {
        int row = row0 + tr + 8 * i;
        if (row < N_NODES) {
#pragma unroll
            for (int j = 0; j < NJ; ++j) {
                int c = tc + 32 * j;
                float bs = 0.25f * (b[c] + b[HO + c] + b[2 * HO + c] + b[3 * HO + c]);
                out[(size_t)row * HO + c] = acc[i][j] + bs;
            }
        }
    }
}

// ----------------------------------------------------------------- launch ---
extern "C" void kernel_launch(void* const* d_in, const int* in_sizes, int n_in,
                              void* d_out, int out_size, void* d_ws, size_t ws_size,
                              hipStream_t stream) {
    const int* src = (const int*)d_in[1];
    const int* dst = (const int*)d_in[2];
    const float* emb = (const float*)d_in[3];
    const float* W1 = (const float*)d_in[4];
    const float* b1 = (const float*)d_in[5];
    const float* W2 = (const float*)d_in[6];
    const float* b2 = (const float*)d_in[7];
    float* out = (float*)d_out;

    int* deg_in = (int*)d_ws;                              // [R][N]
    int* deg_out = deg_in + N_REL * N_NODES;               // [R][N]
    int* offs = deg_out + N_REL * N_NODES;                 // [R][N+1]
    int* cursor = offs + N_REL * (N_NODES + 1);            // [R][N]
    int* csr = cursor + N_REL * N_NODES;                   // [R][E]
    float* nsrc = (float*)(csr + (size_t)N_REL * N_EDGES); // [R][N]
    float* ndst = nsrc + N_REL * N_NODES;                  // [R][N]
    float* h1 = ndst + N_REL * N_NODES;                    // [N][128]

    hipMemsetAsync(deg_in, 0, 2 * N_REL * N_NODES * sizeof(int), stream);
    count_kernel<<<(N_REL * N_EDGES + 255) / 256, 256, 0, stream>>>(src, dst, deg_out, deg_in);
    scan_kernel<<<N_REL, 1024, 0, stream>>>(deg_in, offs);
    norm_cursor_kernel<<<(N_REL * N_NODES + 255) / 256, 256, 0, stream>>>(
        deg_out, deg_in, offs, nsrc, ndst, cursor);
    place_kernel<<<(N_REL * N_EDGES + 255) / 256, 256, 0, stream>>>(src, dst, cursor, csr);

    const int nblk = (N_NODES + 63) / 64;
    rgcn_layer<EMB, HID><<<nblk, 256, 0, stream>>>(emb, csr, offs, nsrc, ndst, W1, b1, h1);
    rgcn_layer<HID, OUTD><<<nblk, 256, 0, stream>>>(h1, csr, offs, nsrc, ndst, W2, b2, out);
}

// Round 3
// 876.144 us; speedup vs baseline: 2.0292x; 1.7721x over previous
//
#include <hip/hip_runtime.h>
#include <hip/hip_bf16.h>

#define N_NODES 50000
#define N_REL   4
#define N_EDGES 500000
#define EMB     128
#define HID     128
#define OUTD    64
#define NC      8            // atomic-spread replicas

// ---- 1) degree counting into NC replicated counters (blockIdx&7 -> copy) ---
__global__ void count_kernel(const int* __restrict__ src, const int* __restrict__ dst,
                             int* __restrict__ cnt_out, int* __restrict__ cnt_in) {
    int e = blockIdx.x * blockDim.x + threadIdx.x;
    int r = blockIdx.y;
    if (e >= N_EDGES) return;
    int c = blockIdx.x & (NC - 1);
    size_t base = ((size_t)c * N_REL + r) * N_NODES;
    atomicAdd(&cnt_out[base + src[(size_t)r * N_EDGES + e]], 1);
    atomicAdd(&cnt_in [base + dst[(size_t)r * N_EDGES + e]], 1);
}

// ---- 2) reduce copies -> totals, norms --------------------------------------
__global__ void reduce_kernel(const int* __restrict__ cnt_out, const int* __restrict__ cnt_in,
                              int* __restrict__ deg_in_tot,
                              float* __restrict__ nsrc, float* __restrict__ ndst) {
    int i = blockIdx.x * blockDim.x + threadIdx.x;
    if (i >= N_REL * N_NODES) return;
    int so = 0, si = 0;
#pragma unroll
    for (int c = 0; c < NC; ++c) {
        so += cnt_out[(size_t)c * N_REL * N_NODES + i];
        si += cnt_in [(size_t)c * N_REL * N_NODES + i];
    }
    deg_in_tot[i] = si;
    nsrc[i] = so > 0 ? rsqrtf((float)so) : 0.0f;
    ndst[i] = si > 0 ? rsqrtf((float)si) : 0.0f;
}

// ---- 3) exclusive scan of deg_in_tot -> offs (one block per relation) -------
__global__ __launch_bounds__(1024) void scan_kernel(const int* __restrict__ deg_in,
                                                    int* __restrict__ offs) {
    __shared__ int sh[1024];
    const int r = blockIdx.x;
    const int t = threadIdx.x;
    const int CH = 49;                          // 49*1024 >= 50001
    const int start = t * CH;
    int sum = 0;
    for (int j = start; j < start + CH; ++j)
        if (j < N_NODES) sum += deg_in[r * N_NODES + j];
    sh[t] = sum;
    __syncthreads();
    for (int off = 1; off < 1024; off <<= 1) {
        int v = (t >= off) ? sh[t - off] : 0;
        __syncthreads();
        sh[t] += v;
        __syncthreads();
    }
    int run = sh[t] - sum;
    for (int j = start; j < start + CH; ++j) {
        if (j <= N_NODES) {
            offs[r * (N_NODES + 1) + j] = run;
            if (j < N_NODES) run += deg_in[r * N_NODES + j];
        }
    }
}

// ---- 4) per-copy cursors ----------------------------------------------------
__global__ void cursor_kernel(const int* __restrict__ cnt_in, const int* __restrict__ offs,
                              int* __restrict__ cursor) {
    int i = blockIdx.x * blockDim.x + threadIdx.x;
    if (i >= N_REL * N_NODES) return;
    int r = i / N_NODES, n = i - r * N_NODES;
    int run = offs[r * (N_NODES + 1) + n];
#pragma unroll
    for (int c = 0; c < NC; ++c) {
        cursor[(size_t)c * N_REL * N_NODES + i] = run;
        run += cnt_in[(size_t)c * N_REL * N_NODES + i];
    }
}

// ---- 5) place edges: csr_rec = {src, nsrc[src]} sorted by dst ---------------
__global__ void place_kernel(const int* __restrict__ src, const int* __restrict__ dst,
                             const float* __restrict__ nsrc,
                             int* __restrict__ cursor, int2* __restrict__ csr_rec) {
    int e = blockIdx.x * blockDim.x + threadIdx.x;
    int r = blockIdx.y;
    if (e >= N_EDGES) return;
    int c = blockIdx.x & (NC - 1);
    int s = src[(size_t)r * N_EDGES + e];
    int d = dst[(size_t)r * N_EDGES + e];
    int p = atomicAdd(&cursor[((size_t)c * N_REL + r) * N_NODES + d], 1);
    csr_rec[(size_t)r * N_EDGES + p] = make_int2(s, __float_as_int(nsrc[(size_t)r * N_NODES + s]));
}

// ---- 6) gather: one wave per dst node; agg_cat[d] = concat_r(0.25*nd_r*sum) -
__global__ __launch_bounds__(256) void gather_kernel(
    const float* __restrict__ x,              // [N][128]
    const int2* __restrict__ csr_rec,         // [R][E]
    const int* __restrict__ offs,             // [R][N+1]
    const float* __restrict__ ndst,           // [R][N]
    float* __restrict__ agg,                  // [chunk][512]
    int node0, int nnodes) {
    int wid = (blockIdx.x * 256 + threadIdx.x) >> 6;
    int lane = threadIdx.x & 63;
    if (wid >= nnodes) return;
    int d = node0 + wid;
    const float2* x2 = (const float2*)x;      // row stride 64 float2
    float2* arow = (float2*)(agg + (size_t)wid * (N_REL * EMB));
#pragma unroll
    for (int r = 0; r < N_REL; ++r) {
        int e0 = offs[r * (N_NODES + 1) + d];
        int e1 = offs[r * (N_NODES + 1) + d + 1];
        const int2* rec = csr_rec + (size_t)r * N_EDGES;
        float ax = 0.0f, ay = 0.0f;
        int e = e0;
        for (; e + 1 < e1; e += 2) {
            int2 r0 = rec[e], r1 = rec[e + 1];
            float w0 = __int_as_float(r0.y), w1 = __int_as_float(r1.y);
            float2 v0 = x2[(size_t)r0.x * 64 + lane];
            float2 v1 = x2[(size_t)r1.x * 64 + lane];
            ax += v0.x * w0 + v1.x * w1;
            ay += v0.y * w0 + v1.y * w1;
        }
        if (e < e1) {
            int2 r0 = rec[e];
            float w0 = __int_as_float(r0.y);
            float2 v0 = x2[(size_t)r0.x * 64 + lane];
            ax += v0.x * w0;
            ay += v0.y * w0;
        }
        float sc = 0.25f * ndst[(size_t)r * N_NODES + d];
        float2 o; o.x = ax * sc; o.y = ay * sc;
        arow[r * 64 + lane] = o;
    }
}

// ---- 7) GEMM: out[chunk][HO] = agg[chunk][512] @ Wflat[512][HO] + bias ------
template <int HO>
__global__ __launch_bounds__(256) void gemm_kernel(
    const float* __restrict__ agg, const float* __restrict__ W,
    const float* __restrict__ b, float* __restrict__ out,
    int node0, int nnodes) {
    constexpr int K = 512, KT = 32;
    constexpr int NJ = HO / 32;
    __shared__ float xt[64][36];
    __shared__ float wt[KT][HO];
    const int t = threadIdx.x;
    const int tc = t & 31;
    const int tr = t >> 5;
    const int row0 = blockIdx.x * 64;

    float acc[8][NJ];
#pragma unroll
    for (int i = 0; i < 8; ++i)
#pragma unroll
        for (int j = 0; j < NJ; ++j) acc[i][j] = 0.0f;

    for (int k0 = 0; k0 < K; k0 += KT) {
#pragma unroll
        for (int q = 0; q < 2; ++q) {           // 64x32 floats = 512 float4
            int idx = t + q * 256;
            int row = idx >> 3, c4 = idx & 7;
            float4 v = make_float4(0.f, 0.f, 0.f, 0.f);
            if (row0 + row < nnodes)
                v = *reinterpret_cast<const float4*>(&agg[(size_t)(row0 + row) * K + k0 + c4 * 4]);
            *reinterpret_cast<float4*>(&xt[row][c4 * 4]) = v;
        }
#pragma unroll
        for (int q = 0; q < (KT * HO / 4) / 256; ++q) {
            int idx = t + q * 256;
            int k = idx / (HO / 4), c4 = idx % (HO / 4);
            float4 v = *reinterpret_cast<const float4*>(&W[(size_t)(k0 + k) * HO + c4 * 4]);
            *reinterpret_cast<float4*>(&wt[k][c4 * 4]) = v;
        }
        __syncthreads();
#pragma unroll
        for (int kk = 0; kk < KT; ++kk) {
            float xv[8];
#pragma unroll
            for (int i = 0; i < 8; ++i) xv[i] = xt[tr + 8 * i][kk];
            float wv[NJ];
#pragma unroll
            for (int j = 0; j < NJ; ++j) wv[j] = wt[kk][tc + 32 * j];
#pragma unroll
            for (int i = 0; i < 8; ++i)
#pragma unroll
                for (int j = 0; j < NJ; ++j) acc[i][j] += xv[i] * wv[j];
        }
        __syncthreads();
    }
#pragma unroll
    for (int i = 0; i < 8; ++i) {
        int row = row0 + tr + 8 * i;
        if (row < nnodes) {
#pragma unroll
            for (int j = 0; j < NJ; ++j) {
                int c = tc + 32 * j;
                float bs = 0.25f * (b[c] + b[HO + c] + b[2 * HO + c] + b[3 * HO + c]);
                out[(size_t)(node0 + row) * HO + c] = acc[i][j] + bs;
            }
        }
    }
}

// ----------------------------------------------------------------- launch ---
extern "C" void kernel_launch(void* const* d_in, const int* in_sizes, int n_in,
                              void* d_out, int out_size, void* d_ws, size_t ws_size,
                              hipStream_t stream) {
    const int* src = (const int*)d_in[1];
    const int* dst = (const int*)d_in[2];
    const float* emb = (const float*)d_in[3];
    const float* W1 = (const float*)d_in[4];
    const float* b1 = (const float*)d_in[5];
    const float* W2 = (const float*)d_in[6];
    const float* b2 = (const float*)d_in[7];
    float* out = (float*)d_out;

    char* p = (char*)d_ws;
    auto alloc = [&](size_t bytes) -> void* {
        void* q = (void*)p;
        p += (bytes + 255) & ~(size_t)255;
        return q;
    };
    int* cnt_out = (int*)alloc((size_t)NC * N_REL * N_NODES * 4);   // 6.4 MB
    int* cnt_in  = (int*)alloc((size_t)NC * N_REL * N_NODES * 4);   // 6.4 MB
    int* deg_in_tot = (int*)alloc((size_t)N_REL * N_NODES * 4);
    int* offs = (int*)alloc((size_t)N_REL * (N_NODES + 1) * 4);
    int* cursor = (int*)alloc((size_t)NC * N_REL * N_NODES * 4);    // 6.4 MB
    int2* csr_rec = (int2*)alloc((size_t)N_REL * N_EDGES * 8);      // 16 MB
    float* nsrc = (float*)alloc((size_t)N_REL * N_NODES * 4);
    float* ndst = (float*)alloc((size_t)N_REL * N_NODES * 4);
    float* h1 = (float*)alloc((size_t)N_NODES * HID * 4);           // 25.6 MB
    size_t used = (size_t)(p - (char*)d_ws);
    size_t avail = ws_size > used ? ws_size - used : 0;
    int npc = (int)((avail / (512 * 4)) > (size_t)N_NODES ? (size_t)N_NODES : (avail / (512 * 4)));
    if (npc < 1) npc = 1;
    float* agg = (float*)p;

    hipMemsetAsync(cnt_out, 0, (size_t)2 * NC * N_REL * N_NODES * 4, stream);
    dim3 egrid((N_EDGES + 255) / 256, N_REL);
    count_kernel<<<egrid, 256, 0, stream>>>(src, dst, cnt_out, cnt_in);
    reduce_kernel<<<(N_REL * N_NODES + 255) / 256, 256, 0, stream>>>(
        cnt_out, cnt_in, deg_in_tot, nsrc, ndst);
    scan_kernel<<<N_REL, 1024, 0, stream>>>(deg_in_tot, offs);
    cursor_kernel<<<(N_REL * N_NODES + 255) / 256, 256, 0, stream>>>(cnt_in, offs, cursor);
    place_kernel<<<egrid, 256, 0, stream>>>(src, dst, nsrc, cursor, csr_rec);

    // layer 1: emb -> h1
    for (int n0 = 0; n0 < N_NODES; n0 += npc) {
        int nn = (N_NODES - n0) < npc ? (N_NODES - n0) : npc;
        gather_kernel<<<(nn + 3) / 4, 256, 0, stream>>>(emb, csr_rec, offs, ndst, agg, n0, nn);
        gemm_kernel<HID><<<(nn + 63) / 64, 256, 0, stream>>>(agg, W1, b1, h1, n0, nn);
    }
    // layer 2: h1 -> out
    for (int n0 = 0; n0 < N_NODES; n0 += npc) {
        int nn = (N_NODES - n0) < npc ? (N_NODES - n0) : npc;
        gather_kernel<<<(nn + 3) / 4, 256, 0, stream>>>(h1, csr_rec, offs, ndst, agg, n0, nn);
        gemm_kernel<OUTD><<<(nn + 63) / 64, 256, 0, stream>>>(agg, W2, b2, out, n0, nn);
    }
}